// Round 2
// baseline (1363.284 us; speedup 1.0000x reference)
//
#include <hip/hip_runtime.h>

// ElmanRNN: BATCH=4096, SEQ=512, IN=2, HID=128, OUT=1
// h_{t+1} = tanh(x_t @ Wx^T + h_t @ Wh^T + b_ih);  out = h_S @ Who^T + b_ho
//
// One kernel launch. 512 blocks x 256 threads (2 blocks/CU); each block owns
// BT=8 batch rows and runs the full 512-step recurrence locally.
// Thread (j = tid&127, g = tid>>7): holds W_h row j STATIONARY IN VGPRS
// (pinned via empty asm so the compiler cannot rematerialize the loads),
// computes hidden unit j for 4 batch rows. h ping-pongs in LDS; all h reads
// are wave-uniform broadcast ds_read_b128 (conflict-free).

constexpr int BATCH   = 4096;
constexpr int SEQ     = 512;
constexpr int INP     = 2;
constexpr int HID     = 128;
constexpr int BT      = 8;    // batch rows per block
constexpr int THREADS = 256;  // 4 waves
constexpr int XCHUNK  = 64;   // time steps of x staged per chunk

__global__ __launch_bounds__(THREADS, 2)
void elman_rnn_kernel(const float* __restrict__ x,
                      const float* __restrict__ W_ih,
                      const float* __restrict__ b_ih,
                      const float* __restrict__ W_ho,
                      const float* __restrict__ b_ho,
                      float* __restrict__ out)
{
    __shared__ float hbuf[2][BT][HID];        // 8 KB: ping-pong hidden state
    __shared__ float xs[BT][XCHUNK * INP];    // 4 KB: staged x chunk

    const int tid = threadIdx.x;
    const int j   = tid & (HID - 1);   // hidden unit owned by this thread
    const int g   = tid >> 7;          // 0/1: which half of the 8 batch rows
    const int b0g = g * 4;             // first local batch row (4 rows each)
    const int blockB0 = blockIdx.x * BT;

    // ---- load weights for hidden unit j (stationary in registers) ----
    const float* Wrow = W_ih + (size_t)j * (INP + HID);
    float wx0 = Wrow[0];
    float wx1 = Wrow[1];
    float bj  = b_ih[j];
    float4 Wr[HID / 4];                // 128 VGPRs of W_h row j
    #pragma unroll
    for (int q = 0; q < HID / 4; ++q) {
        Wr[q] = *reinterpret_cast<const float4*>(Wrow + INP + 4 * q);
    }
    // Pin W (and the x weights) in VGPRs: opaque to the compiler => it cannot
    // rematerialize these as per-step global reloads (R0 failure mode: VGPR=84,
    // W re-streamed from L2 every step, ~4600 cy/step of L2 traffic).
    #pragma unroll
    for (int q = 0; q < HID / 4; ++q) {
        asm volatile("" : "+v"(Wr[q].x), "+v"(Wr[q].y), "+v"(Wr[q].z), "+v"(Wr[q].w));
    }
    asm volatile("" : "+v"(wx0), "+v"(wx1), "+v"(bj));

    // ---- h0 = 0 ----
    #pragma unroll
    for (int bi = 0; bi < 4; ++bi)
        hbuf[0][b0g + bi][j] = 0.0f;   // g=0 covers rows 0-3, g=1 rows 4-7

    const int xrow = tid >> 5;         // 0..7  (batch row for x staging)
    const int xcol = (tid & 31) * 4;   // 0..124 (float4 column)

    int cur = 0;
    #pragma unroll 1
    for (int t0 = 0; t0 < SEQ; t0 += XCHUNK) {
        // stage x[blockB0+row][t0 .. t0+XCHUNK-1][:] -> xs (coalesced float4)
        *reinterpret_cast<float4*>(&xs[xrow][xcol]) =
            *reinterpret_cast<const float4*>(
                x + (size_t)(blockB0 + xrow) * (SEQ * INP) + (size_t)t0 * INP + xcol);
        __syncthreads();  // xs + (first iter) h-init visible

        #pragma unroll 1
        for (int tt = 0; tt < XCHUNK; ++tt) {
            // pre-activation: bias + x-term (uniform float2 LDS reads)
            float acc[4];
            #pragma unroll
            for (int bi = 0; bi < 4; ++bi) {
                const float2 xv =
                    *reinterpret_cast<const float2*>(&xs[b0g + bi][2 * tt]);
                acc[bi] = fmaf(wx0, xv.x, fmaf(wx1, xv.y, bj));
            }

            // recurrent matvec: acc[bi] += sum_k Wh[j][k] * h[bi][k]
            const float4* h0 = reinterpret_cast<const float4*>(hbuf[cur][b0g + 0]);
            const float4* h1 = reinterpret_cast<const float4*>(hbuf[cur][b0g + 1]);
            const float4* h2 = reinterpret_cast<const float4*>(hbuf[cur][b0g + 2]);
            const float4* h3 = reinterpret_cast<const float4*>(hbuf[cur][b0g + 3]);
            #pragma unroll
            for (int q = 0; q < HID / 4; ++q) {
                const float4 w = Wr[q];
                float4 a;
                a = h0[q];
                acc[0] = fmaf(w.x, a.x, fmaf(w.y, a.y, fmaf(w.z, a.z, fmaf(w.w, a.w, acc[0]))));
                a = h1[q];
                acc[1] = fmaf(w.x, a.x, fmaf(w.y, a.y, fmaf(w.z, a.z, fmaf(w.w, a.w, acc[1]))));
                a = h2[q];
                acc[2] = fmaf(w.x, a.x, fmaf(w.y, a.y, fmaf(w.z, a.z, fmaf(w.w, a.w, acc[2]))));
                a = h3[q];
                acc[3] = fmaf(w.x, a.x, fmaf(w.y, a.y, fmaf(w.z, a.z, fmaf(w.w, a.w, acc[3]))));
            }

            // tanh + write h_new   (tanh(a) = 1 - 2/(exp(2a)+1); saturates ok)
            const int nxt = cur ^ 1;
            #pragma unroll
            for (int bi = 0; bi < 4; ++bi) {
                const float e  = __expf(2.0f * acc[bi]);
                const float hn = 1.0f - __fdividef(2.0f, e + 1.0f);
                hbuf[nxt][b0g + bi][j] = hn;
            }
            __syncthreads();
            cur = nxt;
        }
    }

    // ---- output projection: out[b] = Who . h_final[b] + b_ho ----
    if (tid < BT) {
        const int b = tid;
        float s = b_ho[0];
        const float* hr = hbuf[cur][b];
        #pragma unroll 8
        for (int k = 0; k < HID; ++k)
            s = fmaf(W_ho[k], hr[k], s);
        out[blockB0 + b] = s;
    }
}

extern "C" void kernel_launch(void* const* d_in, const int* in_sizes, int n_in,
                              void* d_out, int out_size, void* d_ws, size_t ws_size,
                              hipStream_t stream)
{
    (void)in_sizes; (void)n_in; (void)out_size; (void)d_ws; (void)ws_size;
    const float* x    = (const float*)d_in[0];
    const float* W_ih = (const float*)d_in[1];
    const float* b_ih = (const float*)d_in[2];
    const float* W_ho = (const float*)d_in[3];
    const float* b_ho = (const float*)d_in[4];
    float* out = (float*)d_out;

    dim3 grid(BATCH / BT);
    dim3 block(THREADS);
    elman_rnn_kernel<<<grid, block, 0, stream>>>(x, W_ih, b_ih, W_ho, b_ho, out);
}

// Round 3
// 1361.173 us; speedup vs baseline: 1.0016x; 1.0016x over previous
//
#include <hip/hip_runtime.h>

// ElmanRNN: BATCH=4096, SEQ=512, IN=2, HID=128, OUT=1
// h_{t+1} = tanh(x_t @ Wx^T + h_t @ Wh^T + b_ih);  out = h_S @ Who^T + b_ho
//
// One kernel launch. 512 blocks x 256 threads (2 blocks/CU); each block owns
// BT=8 batch rows and runs the full 512-step recurrence locally.
// Thread (j = tid&127, g = tid>>7): holds W_h row j STATIONARY IN VGPRS.
// R1 lesson: a one-shot asm pin before the loop is not enough — the allocator
// spilled Wr[] and re-streamed it from L2 every step (VGPR=84, ~4600 cy/step/CU
// of L2 traffic, exactly matching observed 6940 cy/step). This version pins
// every W value with an empty asm INSIDE the time loop, forcing per-iteration
// VGPR residency.

constexpr int BATCH   = 4096;
constexpr int SEQ     = 512;
constexpr int INP     = 2;
constexpr int HID     = 128;
constexpr int BT      = 8;    // batch rows per block
constexpr int THREADS = 256;  // 4 waves
constexpr int XCHUNK  = 64;   // time steps of x staged per chunk

#define PIN1(v)  asm volatile("" : "+v"(v))
#define PIN4(v)  asm volatile("" : "+v"((v).x), "+v"((v).y), "+v"((v).z), "+v"((v).w))

__global__ __launch_bounds__(THREADS, 2)
void elman_rnn_kernel(const float* __restrict__ x,
                      const float* __restrict__ W_ih,
                      const float* __restrict__ b_ih,
                      const float* __restrict__ W_ho,
                      const float* __restrict__ b_ho,
                      float* __restrict__ out)
{
    __shared__ float hbuf[2][BT][HID];        // 8 KB: ping-pong hidden state
    __shared__ float xs[BT][XCHUNK * INP];    // 4 KB: staged x chunk

    const int tid = threadIdx.x;
    const int j   = tid & (HID - 1);   // hidden unit owned by this thread
    const int g   = tid >> 7;          // 0/1: which half of the 8 batch rows
    const int b0g = g * 4;             // first local batch row (4 rows each)
    const int blockB0 = blockIdx.x * BT;

    // ---- load weights for hidden unit j (stationary in registers) ----
    const float* Wrow = W_ih + (size_t)j * (INP + HID);
    float wx0 = Wrow[0];
    float wx1 = Wrow[1];
    float bj  = b_ih[j];
    float4 Wr[HID / 4];                // 128 VGPRs of W_h row j
    #pragma unroll
    for (int q = 0; q < HID / 4; ++q) {
        Wr[q] = *reinterpret_cast<const float4*>(Wrow + INP + 4 * q);
    }

    // ---- h0 = 0 ----
    #pragma unroll
    for (int bi = 0; bi < 4; ++bi)
        hbuf[0][b0g + bi][j] = 0.0f;   // g=0 covers rows 0-3, g=1 rows 4-7

    const int xrow = tid >> 5;         // 0..7  (batch row for x staging)
    const int xcol = (tid & 31) * 4;   // 0..124 (float4 column)

    int cur = 0;
    #pragma unroll 1
    for (int t0 = 0; t0 < SEQ; t0 += XCHUNK) {
        // stage x[blockB0+row][t0 .. t0+XCHUNK-1][:] -> xs (coalesced float4)
        *reinterpret_cast<float4*>(&xs[xrow][xcol]) =
            *reinterpret_cast<const float4*>(
                x + (size_t)(blockB0 + xrow) * (SEQ * INP) + (size_t)t0 * INP + xcol);
        __syncthreads();  // xs + (first iter) h-init visible

        #pragma unroll 1
        for (int tt = 0; tt < XCHUNK; ++tt) {
            // Per-iteration pin: forces all 131 W values to stay resident in
            // VGPRs across the whole loop (allocator cannot spill+reload
            // around a per-iteration "+v" constraint).
            #pragma unroll
            for (int q = 0; q < HID / 4; ++q) PIN4(Wr[q]);
            PIN1(wx0); PIN1(wx1); PIN1(bj);

            // pre-activation: bias + x-term (uniform float2 LDS reads)
            float acc[4];
            #pragma unroll
            for (int bi = 0; bi < 4; ++bi) {
                const float2 xv =
                    *reinterpret_cast<const float2*>(&xs[b0g + bi][2 * tt]);
                acc[bi] = fmaf(wx0, xv.x, fmaf(wx1, xv.y, bj));
            }

            // recurrent matvec: acc[bi] += sum_k Wh[j][k] * h[bi][k]
            const float4* h0 = reinterpret_cast<const float4*>(hbuf[cur][b0g + 0]);
            const float4* h1 = reinterpret_cast<const float4*>(hbuf[cur][b0g + 1]);
            const float4* h2 = reinterpret_cast<const float4*>(hbuf[cur][b0g + 2]);
            const float4* h3 = reinterpret_cast<const float4*>(hbuf[cur][b0g + 3]);
            #pragma unroll
            for (int q = 0; q < HID / 4; ++q) {
                const float4 w = Wr[q];
                float4 a;
                a = h0[q];
                acc[0] = fmaf(w.x, a.x, fmaf(w.y, a.y, fmaf(w.z, a.z, fmaf(w.w, a.w, acc[0]))));
                a = h1[q];
                acc[1] = fmaf(w.x, a.x, fmaf(w.y, a.y, fmaf(w.z, a.z, fmaf(w.w, a.w, acc[1]))));
                a = h2[q];
                acc[2] = fmaf(w.x, a.x, fmaf(w.y, a.y, fmaf(w.z, a.z, fmaf(w.w, a.w, acc[2]))));
                a = h3[q];
                acc[3] = fmaf(w.x, a.x, fmaf(w.y, a.y, fmaf(w.z, a.z, fmaf(w.w, a.w, acc[3]))));
            }

            // tanh + write h_new   (tanh(a) = 1 - 2/(exp(2a)+1); saturates ok)
            const int nxt = cur ^ 1;
            #pragma unroll
            for (int bi = 0; bi < 4; ++bi) {
                const float e  = __expf(2.0f * acc[bi]);
                const float hn = 1.0f - __fdividef(2.0f, e + 1.0f);
                hbuf[nxt][b0g + bi][j] = hn;
            }
            __syncthreads();
            cur = nxt;
        }
    }

    // ---- output projection: out[b] = Who . h_final[b] + b_ho ----
    if (tid < BT) {
        const int b = tid;
        float s = b_ho[0];
        const float* hr = hbuf[cur][b];
        #pragma unroll 8
        for (int k = 0; k < HID; ++k)
            s = fmaf(W_ho[k], hr[k], s);
        out[blockB0 + b] = s;
    }
}

extern "C" void kernel_launch(void* const* d_in, const int* in_sizes, int n_in,
                              void* d_out, int out_size, void* d_ws, size_t ws_size,
                              hipStream_t stream)
{
    (void)in_sizes; (void)n_in; (void)out_size; (void)d_ws; (void)ws_size;
    const float* x    = (const float*)d_in[0];
    const float* W_ih = (const float*)d_in[1];
    const float* b_ih = (const float*)d_in[2];
    const float* W_ho = (const float*)d_in[3];
    const float* b_ho = (const float*)d_in[4];
    float* out = (float*)d_out;

    dim3 grid(BATCH / BT);
    dim3 block(THREADS);
    elman_rnn_kernel<<<grid, block, 0, stream>>>(x, W_ih, b_ih, W_ho, b_ho, out);
}

// Round 4
// 1277.252 us; speedup vs baseline: 1.0674x; 1.0657x over previous
//
#include <hip/hip_runtime.h>

// ElmanRNN: BATCH=4096, SEQ=512, IN=2, HID=128, OUT=1
// h_{t+1} = tanh(x_t @ Wx^T + h_t @ Wh^T + b_ih);  out = h_S @ Who^T + b_ho
//
// R0-R2 lesson: the compiler refuses to keep the 128-float stationary W row
// in VGPRs (VGPR_Count=84) and re-streams it from L2 every step (~4600
// cy/step/CU, matching observed 6940 cy/step vs 2048 cy FMA floor). Empty-asm
// "+v" pins don't help: the value can be rematerialized by a fresh load right
// before each asm. THIS version loads W via VOLATILE INLINE-ASM
// global_load_dwordx2 — a volatile asm result cannot be rematerialized, so
// the RA must keep all 128 floats VGPR-resident (budget 256 @ launch_bounds
// (256,2); we need ~170).
//
// dwordx2, not x4: W_ih rows are 130 floats (520 B) apart, so the recurrent
// 128-float block is only 8 B-aligned for even rows.

constexpr int BATCH   = 4096;
constexpr int SEQ     = 512;
constexpr int INP     = 2;
constexpr int HID     = 128;
constexpr int BT      = 8;    // batch rows per block
constexpr int THREADS = 256;  // 4 waves
constexpr int XCHUNK  = 64;   // time steps of x staged per chunk

typedef float f2 __attribute__((ext_vector_type(2)));

__global__ __launch_bounds__(THREADS, 2)
void elman_rnn_kernel(const float* __restrict__ x,
                      const float* __restrict__ W_ih,
                      const float* __restrict__ b_ih,
                      const float* __restrict__ W_ho,
                      const float* __restrict__ b_ho,
                      float* __restrict__ out)
{
    __shared__ float hbuf[2][BT][HID];        // 8 KB: ping-pong hidden state
    __shared__ float xs[BT][XCHUNK * INP];    // 4 KB: staged x chunk

    const int tid = threadIdx.x;
    const int j   = tid & (HID - 1);   // hidden unit owned by this thread
    const int g   = tid >> 7;          // 0/1: which half of the 8 batch rows
    const int b0g = g * 4;             // first local batch row (4 rows each)
    const int blockB0 = blockIdx.x * BT;

    // ---- load weights for hidden unit j; W_h row pinned via volatile asm ----
    const float* Wrow = W_ih + (size_t)j * (INP + HID);
    const float wx0 = Wrow[0];
    const float wx1 = Wrow[1];
    const float bj  = b_ih[j];

    f2 Wq[HID / 2];                    // 128 VGPRs of W_h row j, asm-produced
    #pragma unroll
    for (int q = 0; q < HID / 2; ++q) {
        const float* a = Wrow + INP + 2 * q;
        asm volatile("global_load_dwordx2 %0, %1, off" : "=v"(Wq[q]) : "v"(a));
    }
    asm volatile("s_waitcnt vmcnt(0)" ::: "memory");
    __builtin_amdgcn_sched_barrier(0);

    // ---- h0 = 0 ----
    #pragma unroll
    for (int bi = 0; bi < 4; ++bi)
        hbuf[0][b0g + bi][j] = 0.0f;   // g=0 covers rows 0-3, g=1 rows 4-7

    const int xrow = tid >> 5;         // 0..7  (batch row for x staging)
    const int xcol = (tid & 31) * 4;   // 0..124 (float4 column)

    int cur = 0;
    #pragma unroll 1
    for (int t0 = 0; t0 < SEQ; t0 += XCHUNK) {
        // stage x[blockB0+row][t0 .. t0+XCHUNK-1][:] -> xs (coalesced float4)
        *reinterpret_cast<float4*>(&xs[xrow][xcol]) =
            *reinterpret_cast<const float4*>(
                x + (size_t)(blockB0 + xrow) * (SEQ * INP) + (size_t)t0 * INP + xcol);
        __syncthreads();  // xs + (first iter) h-init / prev-step h visible

        #pragma unroll 1
        for (int tt = 0; tt < XCHUNK; ++tt) {
            // pre-activation: bias + x-term (uniform float2 LDS reads)
            float acc[4];
            #pragma unroll
            for (int bi = 0; bi < 4; ++bi) {
                const float2 xv =
                    *reinterpret_cast<const float2*>(&xs[b0g + bi][2 * tt]);
                acc[bi] = fmaf(wx0, xv.x, fmaf(wx1, xv.y, bj));
            }

            // recurrent matvec: acc[bi] += sum_k Wh[j][k] * h[bi][k]
            // h reads are wave-uniform broadcast ds_read_b128 (conflict-free).
            const float4* h0 = reinterpret_cast<const float4*>(hbuf[cur][b0g + 0]);
            const float4* h1 = reinterpret_cast<const float4*>(hbuf[cur][b0g + 1]);
            const float4* h2 = reinterpret_cast<const float4*>(hbuf[cur][b0g + 2]);
            const float4* h3 = reinterpret_cast<const float4*>(hbuf[cur][b0g + 3]);
            #pragma unroll
            for (int q = 0; q < HID / 4; ++q) {
                const f2 wa = Wq[2 * q];       // W[j][4q+0], W[j][4q+1]
                const f2 wb = Wq[2 * q + 1];   // W[j][4q+2], W[j][4q+3]
                float4 a;
                a = h0[q];
                acc[0] = fmaf(wa.x, a.x, fmaf(wa.y, a.y, fmaf(wb.x, a.z, fmaf(wb.y, a.w, acc[0]))));
                a = h1[q];
                acc[1] = fmaf(wa.x, a.x, fmaf(wa.y, a.y, fmaf(wb.x, a.z, fmaf(wb.y, a.w, acc[1]))));
                a = h2[q];
                acc[2] = fmaf(wa.x, a.x, fmaf(wa.y, a.y, fmaf(wb.x, a.z, fmaf(wb.y, a.w, acc[2]))));
                a = h3[q];
                acc[3] = fmaf(wa.x, a.x, fmaf(wa.y, a.y, fmaf(wb.x, a.z, fmaf(wb.y, a.w, acc[3]))));
            }

            // tanh + write h_new   (tanh(a) = 1 - 2/(exp(2a)+1); saturates ok)
            const int nxt = cur ^ 1;
            #pragma unroll
            for (int bi = 0; bi < 4; ++bi) {
                const float e  = __expf(2.0f * acc[bi]);
                const float hn = 1.0f - __fdividef(2.0f, e + 1.0f);
                hbuf[nxt][b0g + bi][j] = hn;
            }
            __syncthreads();
            cur = nxt;
        }
    }

    // ---- output projection: out[b] = Who . h_final[b] + b_ho ----
    if (tid < BT) {
        const int b = tid;
        float s = b_ho[0];
        const float* hr = hbuf[cur][b];
        #pragma unroll 8
        for (int k = 0; k < HID; ++k)
            s = fmaf(W_ho[k], hr[k], s);
        out[blockB0 + b] = s;
    }
}

extern "C" void kernel_launch(void* const* d_in, const int* in_sizes, int n_in,
                              void* d_out, int out_size, void* d_ws, size_t ws_size,
                              hipStream_t stream)
{
    (void)in_sizes; (void)n_in; (void)out_size; (void)d_ws; (void)ws_size;
    const float* x    = (const float*)d_in[0];
    const float* W_ih = (const float*)d_in[1];
    const float* b_ih = (const float*)d_in[2];
    const float* W_ho = (const float*)d_in[3];
    const float* b_ho = (const float*)d_in[4];
    float* out = (float*)d_out;

    dim3 grid(BATCH / BT);
    dim3 block(THREADS);
    elman_rnn_kernel<<<grid, block, 0, stream>>>(x, W_ih, b_ih, W_ho, b_ho, out);
}

// Round 5
// 374.417 us; speedup vs baseline: 3.6411x; 3.4113x over previous
//
#include <hip/hip_runtime.h>

// ElmanRNN via MFMA: BATCH=4096, SEQ=512, IN=2, HID=128, OUT=1
// h_{t+1} = tanh(h_t @ Wh^T + x_t @ Wx^T + b);  out = h_S @ Who^T + b_ho
//
// R0-R3 lesson: the fp32-VALU decomposition is stuck at ~6900 cy/step/CU
// because hipcc refuses to keep a 128-float stationary W row in VGPRs
// (VGPR_Count=84 in all 4 variants) and re-streams it every step. Pivot to
// matrix cores: per step each block does a [16x128]x[128x128] GEMM with
// mfma_f32_16x16x32_bf16, with hi/lo bf16 splitting of BOTH W and h
// (3 products: Whi*hhi + Whi*hlo + Wlo*hhi -> per-step error ~2^-18;
// measured sequence amplification ~45x -> final ~2e-4 << 1.8e-2 threshold).
//
// Layout safety: A and B fragments are filled with the SAME k->slot map, so
// the MFMA contraction (which pairs A/B slots) is correct regardless of the
// hardware's internal k ordering. Only the D-layout is assumed, and it is
// HW-verified (m89): col = lane&15, row = (lane>>4)*4 + reg.
//
// Structure: 256 blocks (1/CU) x 512 threads (8 waves, 2/SIMD). Block owns
// BM=16 batch rows for all 512 steps. Wave w owns output cols [16w,16w+16):
// stationary W fragments = 8 frags x 4 VGPR = 32 VGPR (small enough that the
// RA keeps them). h ping-pongs in LDS as bf16 hi/lo planes, XOR-swizzled
// (byte ^= (r&7)<<4) so both the D-layout scatter writes and the A-layout
// b128 reads are bank-balanced. One barrier per step.

constexpr int BATCH   = 4096;
constexpr int SEQ     = 512;
constexpr int INP     = 2;
constexpr int HID     = 128;
constexpr int BM      = 16;    // batch rows per block
constexpr int THREADS = 512;   // 8 waves
constexpr int XCHUNK  = 128;   // time steps of x staged per chunk

typedef short bf16x8 __attribute__((ext_vector_type(8)));
typedef float f32x4  __attribute__((ext_vector_type(4)));

__device__ inline unsigned short f2bf(float f) {          // round-to-nearest-even
    unsigned u = __float_as_uint(f);
    return (unsigned short)((u + 0x7FFFu + ((u >> 16) & 1u)) >> 16);
}
__device__ inline float bf2f(unsigned short s) {
    return __uint_as_float(((unsigned)s) << 16);
}

__global__ __launch_bounds__(THREADS, 2)
void elman_mfma_kernel(const float* __restrict__ x,
                       const float* __restrict__ W_ih,
                       const float* __restrict__ b_ih,
                       const float* __restrict__ W_ho,
                       const float* __restrict__ b_ho,
                       float* __restrict__ out)
{
    __shared__ unsigned short hlds[2][2][BM][HID];  // [buf][hi/lo][r][j] = 16 KB
    __shared__ float xs[BM][XCHUNK][INP];           // 16 KB staged x chunk
    __shared__ float red[BM][8];                    // epilogue partials

    const int tid  = threadIdx.x;
    const int lane = tid & 63;
    const int w    = tid >> 6;        // wave id 0..7 -> j-tile [16w, 16w+16)
    const int l15  = lane & 15;
    const int g    = lane >> 4;       // 0..3
    const int j    = w * 16 + l15;    // output column this lane holds (D-layout)
    const int B0   = blockIdx.x * BM;

    // ---- stationary W fragments (B-operand), hi/lo bf16 split ----
    // B-frag slot (g,i) of k-tile kt <- W^T[k][j] = Wh[j][k], k = kt*32 + g*8 + i
    bf16x8 bhi[4], blo[4];
    {
        const float* Wrow = W_ih + (size_t)j * (INP + HID) + INP;
        #pragma unroll
        for (int kt = 0; kt < 4; ++kt) {
            const int k0 = kt * 32 + g * 8;
            #pragma unroll
            for (int i = 0; i < 8; ++i) {
                const float wv = Wrow[k0 + i];
                const unsigned short hi = f2bf(wv);
                const float lo = wv - bf2f(hi);
                bhi[kt][i] = (short)hi;
                blo[kt][i] = (short)f2bf(lo);
            }
        }
    }
    const float* Wrow0 = W_ih + (size_t)j * (INP + HID);
    const float wx0 = Wrow0[0];
    const float wx1 = Wrow0[1];
    const float bj  = b_ih[j];

    // ---- h0 = 0: zero buffer 0 (both planes, 8 KB) ----
    reinterpret_cast<float4*>(hlds)[tid] = float4{0.f, 0.f, 0.f, 0.f};

    // ---- stage x chunk 0 ----
    {
        const int row = tid >> 5;             // 0..15
        const int o8  = (tid & 31) * 8;       // float offset within row's 256
        const float* src = x + (size_t)(B0 + row) * (SEQ * INP) + o8;
        float* dst = &xs[row][0][0] + o8;
        *reinterpret_cast<float4*>(dst)     = *reinterpret_cast<const float4*>(src);
        *reinterpret_cast<float4*>(dst + 4) = *reinterpret_cast<const float4*>(src + 4);
    }
    __syncthreads();

    int p = 0;
    float hv[4] = {0.f, 0.f, 0.f, 0.f};   // final-step h values (epilogue)
    const int sw_r = (l15 & 7) << 4;      // A-read swizzle key (r = l15)

    #pragma unroll 1
    for (int t = 0; t < SEQ; ++t) {
        const int tt = t & (XCHUNK - 1);
        if (t && tt == 0) {
            // previous end-of-step barrier guarantees xs is no longer read
            const int row = tid >> 5;
            const int o8  = (tid & 31) * 8;
            const float* src = x + (size_t)(B0 + row) * (SEQ * INP)
                                 + (size_t)(t >> 7) * (XCHUNK * INP) + o8;
            float* dst = &xs[row][0][0] + o8;
            *reinterpret_cast<float4*>(dst)     = *reinterpret_cast<const float4*>(src);
            *reinterpret_cast<float4*>(dst + 4) = *reinterpret_cast<const float4*>(src + 4);
            __syncthreads();
        }

        // ---- read A fragments (h hi/lo) from buf p ----
        // A-frag slot (g,i) of k-tile kt <- h[r][k], r = l15, k = kt*32 + g*8 + i
        // (same k->slot map as B => contraction correct for any HW ordering)
        const char* hp = (const char*)&hlds[p][0][0][0];
        const char* lp = (const char*)&hlds[p][1][0][0];
        bf16x8 ahi[4], alo[4];
        #pragma unroll
        for (int kt = 0; kt < 4; ++kt) {
            const int off = l15 * 256 + ((kt * 64 + g * 16) ^ sw_r);
            ahi[kt] = *reinterpret_cast<const bf16x8*>(hp + off);
            alo[kt] = *reinterpret_cast<const bf16x8*>(lp + off);
        }

        // ---- 3-product split GEMM: Whi*hhi + Whi*hlo + Wlo*hhi ----
        f32x4 a0 = {0.f, 0.f, 0.f, 0.f};
        f32x4 a1 = {0.f, 0.f, 0.f, 0.f};
        f32x4 a2 = {0.f, 0.f, 0.f, 0.f};
        #pragma unroll
        for (int kt = 0; kt < 4; ++kt) {
            a0 = __builtin_amdgcn_mfma_f32_16x16x32_bf16(ahi[kt], bhi[kt], a0, 0, 0, 0);
            a1 = __builtin_amdgcn_mfma_f32_16x16x32_bf16(alo[kt], bhi[kt], a1, 0, 0, 0);
            a2 = __builtin_amdgcn_mfma_f32_16x16x32_bf16(ahi[kt], blo[kt], a2, 0, 0, 0);
        }

        // ---- x-term + bias + tanh + hi/lo split + write buf p^1 ----
        unsigned short* hn = &hlds[p ^ 1][0][0][0];
        unsigned short* ln = &hlds[p ^ 1][1][0][0];
        #pragma unroll
        for (int i = 0; i < 4; ++i) {
            const int rr = g * 4 + i;                      // D-row (batch row)
            const float2 xv = *reinterpret_cast<const float2*>(&xs[rr][tt][0]);
            const float acc = (a0[i] + a1[i] + a2[i])
                            + fmaf(wx0, xv.x, fmaf(wx1, xv.y, bj));
            const float e = __expf(2.0f * acc);
            const float h = 1.0f - __fdividef(2.0f, e + 1.0f);   // tanh(acc)
            hv[i] = h;
            const unsigned short hb = f2bf(h);
            const float lo = h - bf2f(hb);
            const int off = rr * 256 + ((2 * j) ^ ((rr & 7) << 4));
            *(unsigned short*)((char*)hn + off) = hb;
            *(unsigned short*)((char*)ln + off) = f2bf(lo);
        }
        __syncthreads();
        p ^= 1;
    }

    // ---- epilogue: out[r] = sum_j Who[j]*h[r][j] + b_ho ----
    const float who = W_ho[j];
    float pr[4];
    #pragma unroll
    for (int i = 0; i < 4; ++i) {
        float v = who * hv[i];
        v += __shfl_xor(v, 1);
        v += __shfl_xor(v, 2);
        v += __shfl_xor(v, 4);
        v += __shfl_xor(v, 8);     // 16-lane j-reduction within wave's tile
        pr[i] = v;
    }
    if (l15 == 0) {
        #pragma unroll
        for (int i = 0; i < 4; ++i) red[g * 4 + i][w] = pr[i];
    }
    __syncthreads();
    if (tid < BM) {
        float s = b_ho[0];
        #pragma unroll
        for (int q = 0; q < 8; ++q) s += red[tid][q];
        out[B0 + tid] = s;
    }
}

extern "C" void kernel_launch(void* const* d_in, const int* in_sizes, int n_in,
                              void* d_out, int out_size, void* d_ws, size_t ws_size,
                              hipStream_t stream)
{
    (void)in_sizes; (void)n_in; (void)out_size; (void)d_ws; (void)ws_size;
    const float* x    = (const float*)d_in[0];
    const float* W_ih = (const float*)d_in[1];
    const float* b_ih = (const float*)d_in[2];
    const float* W_ho = (const float*)d_in[3];
    const float* b_ho = (const float*)d_in[4];
    float* out = (float*)d_out;

    dim3 grid(BATCH / BM);     // 256 blocks = 1 per CU
    dim3 block(THREADS);
    elman_mfma_kernel<<<grid, block, 0, stream>>>(x, W_ih, b_ih, W_ho, b_ho, out);
}